// Round 1
// baseline (7238.596 us; speedup 1.0000x reference)
//
#include <hip/hip_runtime.h>
#include <math.h>

#define TD 192
#define HD 48
#define KSEL 128

// Map float to orderable unsigned: a > b (float) <=> f2o(a) > f2o(b)
__device__ __forceinline__ unsigned f2o(float f) {
  unsigned u = __float_as_uint(f);
  return (u & 0x80000000u) ? ~u : (u | 0x80000000u);
}

// 2D sinusoidal positional encoding, matches reference _pos_enc.
__global__ void pe_kernel(float* __restrict__ pe, int W) {
  int n = blockIdx.x;
  int t = threadIdx.x;                      // 0..191
  const float c = -0.09594104554885301f;    // -ln(10000)/96
  float val;
  if (t < 96) {
    float dv = expf((float)t * c);
    val = sinf((float)(n % W) * dv);
  } else {
    float dv = expf((float)(t - 96) * c);
    val = cosf((float)(n / W) * dv);
  }
  pe[n * TD + t] = val;
}

// Q = f1@qw+qb+pe ; K = f2@kw+kb+pe ; V = f2@vw+vb
// block = 192 threads (one per out channel), grid = B*N
__global__ void qkv_kernel(const float* __restrict__ feat1, const float* __restrict__ feat2,
                           const float* __restrict__ qw, const float* __restrict__ qb,
                           const float* __restrict__ kw, const float* __restrict__ kb,
                           const float* __restrict__ vw, const float* __restrict__ vb,
                           const float* __restrict__ pe,
                           float* __restrict__ Q, float* __restrict__ K, float* __restrict__ V,
                           int C, int N) {
  int t = threadIdx.x;            // 0..191
  int bn = blockIdx.x;            // b*N + n
  int b = bn / N, n = bn - b * N;
  const float* f1 = feat1 + (size_t)b * C * N + n;
  const float* f2 = feat2 + (size_t)b * C * N + n;
  float q = 0.f, k = 0.f, v = 0.f;
  for (int c = 0; c < C; ++c) {
    float a1 = f1[(size_t)c * N];
    float a2 = f2[(size_t)c * N];
    q = fmaf(a1, qw[c * TD + t], q);
    k = fmaf(a2, kw[c * TD + t], k);
    v = fmaf(a2, vw[c * TD + t], v);
  }
  float p = pe[n * TD + t];
  size_t o = (size_t)bn * TD + t;
  Q[o] = q + qb[t] + p;
  K[o] = k + kb[t] + p;
  V[o] = v + vb[t];
}

// One block per (b, h, query). Scores in LDS, exact top-128 via radix-256
// select on f2o bits (ties -> lowest index, matching jax.lax.top_k),
// softmax over the selected set, gather V.
__global__ __launch_bounds__(256) void attn_kernel(
    const float* __restrict__ Q, const float* __restrict__ K, const float* __restrict__ V,
    float* __restrict__ O, int N) {
  extern __shared__ float s[];              // N floats of scores
  __shared__ float qv[HD];
  __shared__ float out48[HD];
  __shared__ float redbuf[4];
  __shared__ unsigned hist[256];
  __shared__ int idxb[KSEL];
  __shared__ float wb[KSEL];
  __shared__ int cnt_gt, cnt_eq, ccnt;
  __shared__ unsigned sh_kth;
  __shared__ int sh_rem;
  __shared__ float sh_max, sh_z;

  const int tid = threadIdx.x;
  const int qi = blockIdx.x % N;
  const int h = (blockIdx.x / N) & 3;
  const int b = blockIdx.x / (4 * N);
  const float scale = 0.14433756729740643f;  // 1/sqrt(48)

  if (tid < HD) {
    qv[tid] = Q[((size_t)(b * N + qi)) * TD + h * HD + tid];
    out48[tid] = 0.f;
  }
  if (tid == 0) { cnt_gt = 0; cnt_eq = 0; ccnt = 0; sh_kth = 0u; sh_rem = KSEL; sh_z = 0.f; }
  __syncthreads();

  // ---- scores ----
  float lmax = -INFINITY;
  for (int j = tid; j < N; j += 256) {
    const float* kr = K + ((size_t)(b * N + j)) * TD + h * HD;
    float acc = 0.f;
#pragma unroll
    for (int d = 0; d < HD; d += 4) {
      float4 kv = *reinterpret_cast<const float4*>(kr + d);
      acc = fmaf(kv.x, qv[d], acc);
      acc = fmaf(kv.y, qv[d + 1], acc);
      acc = fmaf(kv.z, qv[d + 2], acc);
      acc = fmaf(kv.w, qv[d + 3], acc);
    }
    acc *= scale;
    s[j] = acc;
    lmax = fmaxf(lmax, acc);
  }
  // block max
  for (int off = 32; off > 0; off >>= 1) lmax = fmaxf(lmax, __shfl_down(lmax, off, 64));
  if ((tid & 63) == 0) redbuf[tid >> 6] = lmax;
  __syncthreads();
  if (tid == 0) sh_max = fmaxf(fmaxf(redbuf[0], redbuf[1]), fmaxf(redbuf[2], redbuf[3]));

  // ---- radix select: 128th largest ----
  unsigned mask = 0u;
  for (int shift = 24; shift >= 0; shift -= 8) {
    hist[tid] = 0u;
    __syncthreads();
    unsigned pfx = sh_kth;
    for (int j = tid; j < N; j += 256) {
      unsigned u = f2o(s[j]);
      if ((u & mask) == pfx) atomicAdd(&hist[(u >> shift) & 255u], 1u);
    }
    __syncthreads();
    if (tid == 0) {
      int rem = sh_rem;
      unsigned c = 0;
      int sel = 0;
      for (int bin = 255; bin >= 0; --bin) {
        unsigned nc = c + hist[bin];
        if ((int)nc >= rem) { sel = bin; break; }
        c = nc;
      }
      sh_rem = rem - (int)c;
      sh_kth = pfx | ((unsigned)sel << shift);
    }
    mask |= (0xFFu << shift);
    __syncthreads();
  }
  const unsigned kth = sh_kth;

  // ---- count strictly-greater and equal ----
  int lgt = 0, leq = 0;
  for (int j = tid; j < N; j += 256) {
    unsigned u = f2o(s[j]);
    lgt += (u > kth);
    leq += (u == kth);
  }
  atomicAdd(&cnt_gt, lgt);
  atomicAdd(&cnt_eq, leq);
  __syncthreads();
  const int need_eq = KSEL - cnt_gt;
  const bool simple = (cnt_eq == need_eq);
  const float mx = sh_max;

  // ---- compact selected + exp weights ----
  float lz = 0.f;
  for (int j = tid; j < N; j += 256) {
    unsigned u = f2o(s[j]);
    bool sel = (u > kth);
    if (!sel && u == kth) {
      if (simple) {
        sel = true;
      } else {
        // rare tie path: pick lowest indices among equal values
        int rank = 0;
        for (int jj = 0; jj < j; ++jj) rank += (f2o(s[jj]) == kth);
        sel = (rank < need_eq);
      }
    }
    if (sel) {
      float e = expf(s[j] - mx);
      int p = atomicAdd(&ccnt, 1);
      idxb[p] = j;
      wb[p] = e;
      lz += e;
    }
  }
  atomicAdd(&sh_z, lz);
  __syncthreads();
  const float rz = 1.f / sh_z;

  // ---- gather V, weighted sum ----
  if (tid < 240) {
    int d = tid % HD, g = tid / HD;     // 5 groups of 48 dims
    float acc = 0.f;
    for (int p = g; p < KSEL; p += 5) {
      acc = fmaf(wb[p], V[((size_t)(b * N + idxb[p])) * TD + h * HD + d], acc);
    }
    atomicAdd(&out48[d], acc);
  }
  __syncthreads();
  if (tid < HD) O[((size_t)(b * N + qi)) * TD + h * HD + tid] = out48[tid] * rz;
}

// out[b, t, n] = O[b, n, :] . ow[:, t] + ob[t]
// grid: (ceil(N/256), 192, B), block 256
__global__ void oproj_kernel(const float* __restrict__ O, const float* __restrict__ ow,
                             const float* __restrict__ ob, float* __restrict__ out, int N) {
  __shared__ float wcol[TD];
  const int t = blockIdx.y;
  const int b = blockIdx.z;
  if (threadIdx.x < TD) wcol[threadIdx.x] = ow[threadIdx.x * TD + t];
  __syncthreads();
  int n = blockIdx.x * 256 + threadIdx.x;
  if (n >= N) return;
  const float* orow = O + ((size_t)(b * N + n)) * TD;
  float acc = 0.f;
#pragma unroll 8
  for (int c = 0; c < TD; c += 4) {
    float4 o4 = *reinterpret_cast<const float4*>(orow + c);
    acc = fmaf(o4.x, wcol[c], acc);
    acc = fmaf(o4.y, wcol[c + 1], acc);
    acc = fmaf(o4.z, wcol[c + 2], acc);
    acc = fmaf(o4.w, wcol[c + 3], acc);
  }
  out[((size_t)(b * TD + t)) * N + n] = acc + ob[t];
}

extern "C" void kernel_launch(void* const* d_in, const int* in_sizes, int n_in,
                              void* d_out, int out_size, void* d_ws, size_t ws_size,
                              hipStream_t stream) {
  const int B = 2;
  const int Cs[3] = {64, 128, 192};
  const int Hs[3] = {64, 32, 16};
  const size_t out_off[3] = {0,
                             (size_t)2 * TD * 64 * 64,
                             (size_t)2 * TD * 64 * 64 + (size_t)2 * TD * 32 * 32};

  float* ws = (float*)d_ws;
  float* pe = ws;                                 // 4096*192
  float* Q = pe + (size_t)4096 * TD;              // 2*4096*192
  float* K = Q + (size_t)B * 4096 * TD;
  float* V = K + (size_t)B * 4096 * TD;
  float* Obuf = V + (size_t)B * 4096 * TD;

  for (int lvl = 0; lvl < 3; ++lvl) {
    int C = Cs[lvl], H = Hs[lvl], W = H, N = H * W;
    const float* feat1 = (const float*)d_in[lvl * 2 + 0];
    const float* feat2 = (const float*)d_in[lvl * 2 + 1];
    const float* qw = (const float*)d_in[6 + lvl * 8 + 0];
    const float* qb = (const float*)d_in[6 + lvl * 8 + 1];
    const float* kw = (const float*)d_in[6 + lvl * 8 + 2];
    const float* kb = (const float*)d_in[6 + lvl * 8 + 3];
    const float* vw = (const float*)d_in[6 + lvl * 8 + 4];
    const float* vb = (const float*)d_in[6 + lvl * 8 + 5];
    const float* ow = (const float*)d_in[6 + lvl * 8 + 6];
    const float* ob = (const float*)d_in[6 + lvl * 8 + 7];

    pe_kernel<<<N, TD, 0, stream>>>(pe, W);
    qkv_kernel<<<B * N, TD, 0, stream>>>(feat1, feat2, qw, qb, kw, kb, vw, vb, pe, Q, K, V, C, N);
    attn_kernel<<<B * 4 * N, 256, N * sizeof(float), stream>>>(Q, K, V, Obuf, N);
    dim3 g((N + 255) / 256, TD, B);
    oproj_kernel<<<g, 256, 0, stream>>>(Obuf, ow, ob, (float*)d_out + out_off[lvl], N);
  }
}

// Round 2
// 3597.494 us; speedup vs baseline: 2.0121x; 2.0121x over previous
//
#include <hip/hip_runtime.h>
#include <math.h>

#define TD 192
#define HD 48
#define KSEL 128
#define QB 4

// Map float to orderable unsigned: a > b (float) <=> f2o(a) > f2o(b)
__device__ __forceinline__ unsigned f2o(float f) {
  unsigned u = __float_as_uint(f);
  return (u & 0x80000000u) ? ~u : (u | 0x80000000u);
}

// 2D sinusoidal positional encoding, matches reference _pos_enc.
__global__ void pe_kernel(float* __restrict__ pe, int W) {
  int n = blockIdx.x;
  int t = threadIdx.x;                      // 0..191
  const float c = -0.09594104554885301f;    // -ln(10000)/96
  float val;
  if (t < 96) {
    float dv = expf((float)t * c);
    val = sinf((float)(n % W) * dv);
  } else {
    float dv = expf((float)(t - 96) * c);
    val = cosf((float)(n / W) * dv);
  }
  pe[n * TD + t] = val;
}

// Q = f1@qw+qb+pe (row-major [b][n][td])
// Kt = transpose of (f2@kw+kb+pe) -> [b][h][d][N]
// V = f2@vw+vb (row-major)
__global__ void qkv_kernel(const float* __restrict__ feat1, const float* __restrict__ feat2,
                           const float* __restrict__ qw, const float* __restrict__ qb,
                           const float* __restrict__ kw, const float* __restrict__ kb,
                           const float* __restrict__ vw, const float* __restrict__ vb,
                           const float* __restrict__ pe,
                           float* __restrict__ Q, float* __restrict__ Kt, float* __restrict__ V,
                           int C, int N) {
  int t = threadIdx.x;            // 0..191
  int bn = blockIdx.x;            // b*N + n
  int b = bn / N, n = bn - b * N;
  const float* f1 = feat1 + (size_t)b * C * N + n;
  const float* f2 = feat2 + (size_t)b * C * N + n;
  float q = 0.f, k = 0.f, v = 0.f;
  for (int c = 0; c < C; ++c) {
    float a1 = f1[(size_t)c * N];
    float a2 = f2[(size_t)c * N];
    q = fmaf(a1, qw[c * TD + t], q);
    k = fmaf(a2, kw[c * TD + t], k);
    v = fmaf(a2, vw[c * TD + t], v);
  }
  float p = pe[n * TD + t];
  size_t o = (size_t)bn * TD + t;
  Q[o] = q + qb[t] + p;
  V[o] = v + vb[t];
  int h = t / HD, d = t - h * HD;
  Kt[(((size_t)b * 4 + h) * HD + d) * N + n] = k + kb[t] + p;
}

// One block per (b, h, group of QB=4 queries). Coalesced K^T score GEMM into
// LDS, then one WAVE per query does radix-select top-128 (ties -> lowest
// index), softmax, V gather. 256 threads = 4 waves.
__global__ __launch_bounds__(256) void attn_kernel(
    const float* __restrict__ Q, const float* __restrict__ Kt, const float* __restrict__ V,
    float* __restrict__ O, int N) {
  extern __shared__ float s[];              // QB * N scores
  __shared__ float qv[QB][HD];
  __shared__ float redmax[4][QB];
  __shared__ unsigned hist[4 * 256];
  __shared__ int idxb[4][KSEL];
  __shared__ float wb[4][KSEL];
  __shared__ int ccnt[4];

  const int tid = threadIdx.x;
  const int nq = N / QB;
  const int qg = blockIdx.x % nq;
  const int h = (blockIdx.x / nq) & 3;
  const int b = blockIdx.x / (4 * nq);
  const int q0 = qg * QB;
  const float scale = 0.14433756729740643f;  // 1/sqrt(48)

  if (tid < QB * HD) {
    int q = tid / HD, d = tid - q * HD;
    qv[q][d] = Q[((size_t)(b * N + q0 + q)) * TD + h * HD + d];
  }
  __syncthreads();

  // ---- scores: s[q][j] for 4 keys per lane per sweep, coalesced Kt loads ----
  const float* kt = Kt + ((size_t)(b * 4 + h) * HD) * N;
  float lmax[QB] = {-INFINITY, -INFINITY, -INFINITY, -INFINITY};
  for (int j0 = tid * 4; j0 < N; j0 += 1024) {
    float4 acc[QB];
#pragma unroll
    for (int q = 0; q < QB; ++q) acc[q] = make_float4(0.f, 0.f, 0.f, 0.f);
#pragma unroll
    for (int d4 = 0; d4 < HD; d4 += 4) {
      float4 k0 = *reinterpret_cast<const float4*>(kt + (size_t)(d4 + 0) * N + j0);
      float4 k1 = *reinterpret_cast<const float4*>(kt + (size_t)(d4 + 1) * N + j0);
      float4 k2 = *reinterpret_cast<const float4*>(kt + (size_t)(d4 + 2) * N + j0);
      float4 k3 = *reinterpret_cast<const float4*>(kt + (size_t)(d4 + 3) * N + j0);
#pragma unroll
      for (int q = 0; q < QB; ++q) {
        float4 qq = *reinterpret_cast<const float4*>(&qv[q][d4]);
        acc[q].x = fmaf(qq.x, k0.x, acc[q].x); acc[q].x = fmaf(qq.y, k1.x, acc[q].x);
        acc[q].x = fmaf(qq.z, k2.x, acc[q].x); acc[q].x = fmaf(qq.w, k3.x, acc[q].x);
        acc[q].y = fmaf(qq.x, k0.y, acc[q].y); acc[q].y = fmaf(qq.y, k1.y, acc[q].y);
        acc[q].y = fmaf(qq.z, k2.y, acc[q].y); acc[q].y = fmaf(qq.w, k3.y, acc[q].y);
        acc[q].z = fmaf(qq.x, k0.z, acc[q].z); acc[q].z = fmaf(qq.y, k1.z, acc[q].z);
        acc[q].z = fmaf(qq.z, k2.z, acc[q].z); acc[q].z = fmaf(qq.w, k3.z, acc[q].z);
        acc[q].w = fmaf(qq.x, k0.w, acc[q].w); acc[q].w = fmaf(qq.y, k1.w, acc[q].w);
        acc[q].w = fmaf(qq.z, k2.w, acc[q].w); acc[q].w = fmaf(qq.w, k3.w, acc[q].w);
      }
    }
#pragma unroll
    for (int q = 0; q < QB; ++q) {
      acc[q].x *= scale; acc[q].y *= scale; acc[q].z *= scale; acc[q].w *= scale;
      lmax[q] = fmaxf(lmax[q], fmaxf(fmaxf(acc[q].x, acc[q].y), fmaxf(acc[q].z, acc[q].w)));
      *reinterpret_cast<float4*>(&s[q * N + j0]) = acc[q];
    }
  }
  {
    const int w = tid >> 6, lane = tid & 63;
#pragma unroll
    for (int q = 0; q < QB; ++q) {
      float m = lmax[q];
      for (int off = 32; off > 0; off >>= 1) m = fmaxf(m, __shfl_xor(m, off, 64));
      if (lane == 0) redmax[w][q] = m;
    }
  }
  __syncthreads();

  // ---- per-wave: wave w selects top-128 for query w ----
  const int w = tid >> 6, lane = tid & 63;
  float* sq = s + w * N;
  const float mx = fmaxf(fmaxf(redmax[0][w], redmax[1][w]), fmaxf(redmax[2][w], redmax[3][w]));
  unsigned* hw = hist + w * 256;
  unsigned kth = 0u;
  int rem = KSEL, gt = 0, eqv = 0;
  unsigned mask = 0u;
#pragma unroll
  for (int shift = 24; shift >= 0; shift -= 8) {
    for (int i = lane; i < 256; i += 64) hw[i] = 0u;
    for (int j = lane; j < N; j += 64) {
      unsigned u = f2o(sq[j]);
      if ((u & mask) == kth) atomicAdd(&hw[(u >> shift) & 255u], 1u);
    }
    // suffix scan over 256 bins, 4 bins/lane in descending order
    int v[4], loc = 0;
#pragma unroll
    for (int i = 0; i < 4; ++i) { v[i] = (int)hw[255 - (lane * 4 + i)]; loc += v[i]; }
    int incl = loc;
#pragma unroll
    for (int off = 1; off < 64; off <<= 1) {
      int t = __shfl_up(incl, off, 64);
      if (lane >= off) incl += t;
    }
    int c = incl - loc;  // count in bins strictly above this lane's bins
    int selidx = -1, selexcl = 0, selval = 0;
#pragma unroll
    for (int i = 0; i < 4; ++i) {
      if (selidx < 0 && rem > c && rem <= c + v[i]) {
        selidx = 255 - (lane * 4 + i); selexcl = c; selval = v[i];
      }
      c += v[i];
    }
    unsigned long long vote = __ballot(selidx >= 0);
    int src = __ffsll((long long)vote) - 1;
    selidx = __shfl(selidx, src, 64);
    selexcl = __shfl(selexcl, src, 64);
    selval = __shfl(selval, src, 64);
    gt += selexcl;
    rem -= selexcl;
    kth |= ((unsigned)selidx << shift);
    mask |= (0xFFu << shift);
    eqv = selval;
  }

  // ---- compact selected + exp weights (per wave) ----
  const int need_eq = KSEL - gt;
  const bool simple = (eqv == need_eq);
  if (lane == 0) ccnt[w] = 0;
  float lz = 0.f;
  for (int j = lane; j < N; j += 64) {
    unsigned u = f2o(sq[j]);
    bool sel = (u > kth);
    if (!sel && u == kth) {
      if (simple) {
        sel = true;
      } else {
        int rank = 0;
        for (int jj = 0; jj < j; ++jj) rank += (f2o(sq[jj]) == kth);
        sel = (rank < need_eq);
      }
    }
    if (sel) {
      float e = expf(sq[j] - mx);
      int p = atomicAdd(&ccnt[w], 1);
      idxb[w][p] = j;
      wb[w][p] = e;
      lz += e;
    }
  }
  for (int off = 32; off > 0; off >>= 1) lz += __shfl_xor(lz, off, 64);
  const float rz = 1.f / lz;

  // ---- gather V (per wave, lane = dim) ----
  if (lane < HD) {
    float acc = 0.f;
#pragma unroll 4
    for (int p = 0; p < KSEL; ++p) {
      acc = fmaf(wb[w][p], V[((size_t)(b * N + idxb[w][p])) * TD + h * HD + lane], acc);
    }
    O[((size_t)(b * N + q0 + w)) * TD + h * HD + lane] = acc * rz;
  }
}

// out[b, t, n0+nl] = O[b, n0+nl, :] . ow[:, t] + ob[t]; 64-token LDS tile.
#define TOK 64
__global__ __launch_bounds__(256) void oproj_kernel(
    const float* __restrict__ O, const float* __restrict__ ow,
    const float* __restrict__ ob, float* __restrict__ out, int N) {
  __shared__ float otile[TOK][TD + 1];
  const int tid = threadIdx.x;
  const int nt = N / TOK;
  const int b = blockIdx.x / nt;
  const int n0 = (blockIdx.x % nt) * TOK;
  const float* obase = O + ((size_t)(b * N + n0)) * TD;
  for (int idx = tid * 4; idx < TOK * TD; idx += 1024) {
    float4 v = *reinterpret_cast<const float4*>(obase + idx);
    int r = idx / TD, c = idx - r * TD;
    otile[r][c] = v.x; otile[r][c + 1] = v.y; otile[r][c + 2] = v.z; otile[r][c + 3] = v.w;
  }
  __syncthreads();
  const int nl = tid >> 2;            // 0..63 token
  const int ts = (tid & 3) * 48;      // output-channel group
  float acc[48];
#pragma unroll
  for (int i = 0; i < 48; ++i) acc[i] = 0.f;
  for (int c = 0; c < TD; ++c) {
    float oval = otile[nl][c];
    const float* wr = ow + c * TD + ts;
#pragma unroll
    for (int i = 0; i < 48; ++i) acc[i] = fmaf(oval, wr[i], acc[i]);
  }
#pragma unroll
  for (int i = 0; i < 48; ++i) {
    int t = ts + i;
    out[((size_t)(b * TD + t)) * N + n0 + nl] = acc[i] + ob[t];
  }
}

extern "C" void kernel_launch(void* const* d_in, const int* in_sizes, int n_in,
                              void* d_out, int out_size, void* d_ws, size_t ws_size,
                              hipStream_t stream) {
  const int B = 2;
  const int Cs[3] = {64, 128, 192};
  const int Hs[3] = {64, 32, 16};
  const size_t out_off[3] = {0,
                             (size_t)2 * TD * 64 * 64,
                             (size_t)2 * TD * 64 * 64 + (size_t)2 * TD * 32 * 32};

  float* ws = (float*)d_ws;
  float* pe = ws;                                 // 4096*192
  float* Q = pe + (size_t)4096 * TD;              // 2*4096*192
  float* Kt = Q + (size_t)B * 4096 * TD;
  float* V = Kt + (size_t)B * 4096 * TD;
  float* Obuf = V + (size_t)B * 4096 * TD;

  for (int lvl = 0; lvl < 3; ++lvl) {
    int C = Cs[lvl], H = Hs[lvl], W = H, N = H * W;
    const float* feat1 = (const float*)d_in[lvl * 2 + 0];
    const float* feat2 = (const float*)d_in[lvl * 2 + 1];
    const float* qw = (const float*)d_in[6 + lvl * 8 + 0];
    const float* qb = (const float*)d_in[6 + lvl * 8 + 1];
    const float* kw = (const float*)d_in[6 + lvl * 8 + 2];
    const float* kb = (const float*)d_in[6 + lvl * 8 + 3];
    const float* vw = (const float*)d_in[6 + lvl * 8 + 4];
    const float* vb = (const float*)d_in[6 + lvl * 8 + 5];
    const float* ow = (const float*)d_in[6 + lvl * 8 + 6];
    const float* ob = (const float*)d_in[6 + lvl * 8 + 7];

    pe_kernel<<<N, TD, 0, stream>>>(pe, W);
    qkv_kernel<<<B * N, TD, 0, stream>>>(feat1, feat2, qw, qb, kw, kb, vw, vb, pe, Q, Kt, V, C, N);
    attn_kernel<<<B * 4 * (N / QB), 256, QB * N * sizeof(float), stream>>>(Q, Kt, V, Obuf, N);
    oproj_kernel<<<B * (N / TOK), 256, 0, stream>>>(Obuf, ow, ob, (float*)d_out + out_off[lvl], N);
  }
}

// Round 3
// 2925.343 us; speedup vs baseline: 2.4744x; 1.2298x over previous
//
#include <hip/hip_runtime.h>
#include <math.h>

#define TD 192
#define HD 48
#define KSEL 128
#define QB 4

// Map float to orderable unsigned: a > b (float) <=> f2o(a) > f2o(b)
__device__ __forceinline__ unsigned f2o(float f) {
  unsigned u = __float_as_uint(f);
  return (u & 0x80000000u) ? ~u : (u | 0x80000000u);
}
__device__ __forceinline__ float o2f(unsigned u) {
  unsigned v = (u & 0x80000000u) ? (u & 0x7fffffffu) : ~u;
  return __uint_as_float(v);
}

// 2D sinusoidal positional encoding, matches reference _pos_enc.
__global__ void pe_kernel(float* __restrict__ pe, int W) {
  int n = blockIdx.x;
  int t = threadIdx.x;                      // 0..191
  const float c = -0.09594104554885301f;    // -ln(10000)/96
  float val;
  if (t < 96) {
    float dv = expf((float)t * c);
    val = sinf((float)(n % W) * dv);
  } else {
    float dv = expf((float)(t - 96) * c);
    val = cosf((float)(n / W) * dv);
  }
  pe[n * TD + t] = val;
}

// Q = f1@qw+qb+pe (row-major [b][n][td])
// Kt = transpose of (f2@kw+kb+pe) -> [b][h][d][N]
// V = f2@vw+vb (row-major)
__global__ void qkv_kernel(const float* __restrict__ feat1, const float* __restrict__ feat2,
                           const float* __restrict__ qw, const float* __restrict__ qb,
                           const float* __restrict__ kw, const float* __restrict__ kb,
                           const float* __restrict__ vw, const float* __restrict__ vb,
                           const float* __restrict__ pe,
                           float* __restrict__ Q, float* __restrict__ Kt, float* __restrict__ V,
                           int C, int N) {
  int t = threadIdx.x;            // 0..191
  int bn = blockIdx.x;            // b*N + n
  int b = bn / N, n = bn - b * N;
  const float* f1 = feat1 + (size_t)b * C * N + n;
  const float* f2 = feat2 + (size_t)b * C * N + n;
  float q = 0.f, k = 0.f, v = 0.f;
  for (int c = 0; c < C; ++c) {
    float a1 = f1[(size_t)c * N];
    float a2 = f2[(size_t)c * N];
    q = fmaf(a1, qw[c * TD + t], q);
    k = fmaf(a2, kw[c * TD + t], k);
    v = fmaf(a2, vw[c * TD + t], v);
  }
  float p = pe[n * TD + t];
  size_t o = (size_t)bn * TD + t;
  Q[o] = q + qb[t] + p;
  V[o] = v + vb[t];
  int h = t / HD, d = t - h * HD;
  Kt[(((size_t)b * 4 + h) * HD + d) * N + n] = k + kb[t] + p;
}

// One block per (b, h, group of QB=4 queries). Cooperative coalesced score
// GEMM -> LDS as f2o keys; then one WAVE per query keeps its N keys in
// REGISTERS: radix-select top-128 (LDS atomics only for 256-bin histograms,
// passes 2-4 predicated on prefix match), ballot-based compact with exact
// lowest-index tie ranking, softmax, V gather. No __syncthreads after handoff.
template <int N>
__global__ __launch_bounds__(256) void attn_kernel(
    const float* __restrict__ Q, const float* __restrict__ Kt, const float* __restrict__ V,
    float* __restrict__ O) {
  constexpr int NV = N / 64;                // keys per lane
  extern __shared__ unsigned sb[];          // QB * N keys
  __shared__ float qv[QB][HD];
  __shared__ unsigned hist[4][256];
  __shared__ int idxb[4][KSEL];
  __shared__ float wb[4][KSEL];

  const int tid = threadIdx.x;
  const int nq = N / QB;
  const int qg = blockIdx.x % nq;
  const int h = (blockIdx.x / nq) & 3;
  const int b = blockIdx.x / (4 * nq);
  const int q0 = qg * QB;
  const float scale = 0.14433756729740643f;  // 1/sqrt(48)

  if (tid < QB * HD) {
    int q = tid / HD, d = tid - q * HD;
    qv[q][d] = Q[((size_t)(b * N + q0 + q)) * TD + h * HD + d];
  }
  __syncthreads();

  // ---- scores: 4 keys/lane/sweep, coalesced Kt loads, store f2o keys ----
  const float* kt = Kt + ((size_t)(b * 4 + h) * HD) * N;
  for (int j0 = tid * 4; j0 < N; j0 += 1024) {
    float4 acc[QB];
#pragma unroll
    for (int q = 0; q < QB; ++q) acc[q] = make_float4(0.f, 0.f, 0.f, 0.f);
#pragma unroll
    for (int d4 = 0; d4 < HD; d4 += 4) {
      float4 k0 = *reinterpret_cast<const float4*>(kt + (size_t)(d4 + 0) * N + j0);
      float4 k1 = *reinterpret_cast<const float4*>(kt + (size_t)(d4 + 1) * N + j0);
      float4 k2 = *reinterpret_cast<const float4*>(kt + (size_t)(d4 + 2) * N + j0);
      float4 k3 = *reinterpret_cast<const float4*>(kt + (size_t)(d4 + 3) * N + j0);
#pragma unroll
      for (int q = 0; q < QB; ++q) {
        float4 qq = *reinterpret_cast<const float4*>(&qv[q][d4]);
        acc[q].x = fmaf(qq.x, k0.x, acc[q].x); acc[q].x = fmaf(qq.y, k1.x, acc[q].x);
        acc[q].x = fmaf(qq.z, k2.x, acc[q].x); acc[q].x = fmaf(qq.w, k3.x, acc[q].x);
        acc[q].y = fmaf(qq.x, k0.y, acc[q].y); acc[q].y = fmaf(qq.y, k1.y, acc[q].y);
        acc[q].y = fmaf(qq.z, k2.y, acc[q].y); acc[q].y = fmaf(qq.w, k3.y, acc[q].y);
        acc[q].z = fmaf(qq.x, k0.z, acc[q].z); acc[q].z = fmaf(qq.y, k1.z, acc[q].z);
        acc[q].z = fmaf(qq.z, k2.z, acc[q].z); acc[q].z = fmaf(qq.w, k3.z, acc[q].z);
        acc[q].w = fmaf(qq.x, k0.w, acc[q].w); acc[q].w = fmaf(qq.y, k1.w, acc[q].w);
        acc[q].w = fmaf(qq.z, k2.w, acc[q].w); acc[q].w = fmaf(qq.w, k3.w, acc[q].w);
      }
    }
#pragma unroll
    for (int q = 0; q < QB; ++q) {
      uint4 kk;
      kk.x = f2o(acc[q].x * scale); kk.y = f2o(acc[q].y * scale);
      kk.z = f2o(acc[q].z * scale); kk.w = f2o(acc[q].w * scale);
      *reinterpret_cast<uint4*>(&sb[q * N + j0]) = kk;
    }
  }
  __syncthreads();

  // ---- per-wave selection: wave w owns query w; keys -> registers ----
  const int w = tid >> 6, lane = tid & 63;
  const unsigned long long lanelt = (1ull << lane) - 1ull;
  unsigned* sq = sb + w * N;
  unsigned key[NV];
#pragma unroll
  for (int i = 0; i < NV; ++i) key[i] = sq[i * 64 + lane];

  // global max via key max (f2o order-preserving)
  unsigned mk = 0u;
#pragma unroll
  for (int i = 0; i < NV; ++i) mk = key[i] > mk ? key[i] : mk;
  for (int off = 32; off > 0; off >>= 1) {
    unsigned o = (unsigned)__shfl_xor((int)mk, off, 64);
    mk = o > mk ? o : mk;
  }
  const float mx = o2f(mk);

  // ---- radix select: kth-largest key (k=128) ----
  unsigned* hw = hist[w];
  unsigned kth = 0u, mask = 0u;
  int rem = KSEL, gt = 0;
#pragma unroll
  for (int shift = 24; shift >= 0; shift -= 8) {
#pragma unroll
    for (int i = 0; i < 4; ++i) hw[lane + i * 64] = 0u;
    if (shift == 24) {
#pragma unroll
      for (int i = 0; i < NV; ++i) atomicAdd(&hw[key[i] >> 24], 1u);
    } else {
#pragma unroll
      for (int i = 0; i < NV; ++i)
        if ((key[i] & mask) == kth) atomicAdd(&hw[(key[i] >> shift) & 255u], 1u);
    }
    // wave suffix-scan over 256 bins, 4 bins/lane descending
    int v[4], loc = 0;
#pragma unroll
    for (int i = 0; i < 4; ++i) { v[i] = (int)hw[255 - (lane * 4 + i)]; loc += v[i]; }
    int incl = loc;
#pragma unroll
    for (int off = 1; off < 64; off <<= 1) {
      int t = __shfl_up(incl, off, 64);
      if (lane >= off) incl += t;
    }
    int c = incl - loc;  // count in bins strictly above this lane's bins
    int selidx = -1, selexcl = 0;
#pragma unroll
    for (int i = 0; i < 4; ++i) {
      if (selidx < 0 && rem > c && rem <= c + v[i]) {
        selidx = 255 - (lane * 4 + i); selexcl = c;
      }
      c += v[i];
    }
    unsigned long long vote = __ballot(selidx >= 0);
    int src = __ffsll((long long)vote) - 1;
    selidx = __shfl(selidx, src, 64);
    selexcl = __shfl(selexcl, src, 64);
    gt += selexcl;
    rem -= selexcl;
    kth |= ((unsigned)selidx << shift);
    mask |= (0xFFu << shift);
  }
  const int need_eq = rem;   // = KSEL - gt boundary slots, lowest index first

  // ---- compact: ballot positions, exact tie ranking, exp weights ----
  int selbase = 0, eqbase = 0;
  float lz = 0.f;
#pragma unroll
  for (int i = 0; i < NV; ++i) {
    unsigned u = key[i];
    bool eq = (u == kth);
    unsigned long long beq = __ballot(eq);
    int eqrank = eqbase + __popcll(beq & lanelt);
    eqbase += __popcll(beq);
    bool sel = (u > kth) || (eq && eqrank < need_eq);
    unsigned long long bsel = __ballot(sel);
    int pos = selbase + __popcll(bsel & lanelt);
    selbase += __popcll(bsel);
    if (sel) {
      float e = expf(o2f(u) - mx);
      idxb[w][pos] = i * 64 + lane;
      wb[w][pos] = e;
      lz += e;
    }
  }
  for (int off = 32; off > 0; off >>= 1) lz += __shfl_xor(lz, off, 64);
  const float rz = 1.f / lz;

  // ---- gather V (per wave, lane = dim) ----
  if (lane < HD) {
    float acc = 0.f;
#pragma unroll 4
    for (int p = 0; p < KSEL; ++p) {
      acc = fmaf(wb[w][p], V[((size_t)(b * N + idxb[w][p])) * TD + h * HD + lane], acc);
    }
    O[((size_t)(b * N + q0 + w)) * TD + h * HD + lane] = acc * rz;
  }
}

// out[b, t, n0+nl] = O[b, n0+nl, :] . ow[:, t] + ob[t]; 64-token LDS tile.
#define TOK 64
__global__ __launch_bounds__(256) void oproj_kernel(
    const float* __restrict__ O, const float* __restrict__ ow,
    const float* __restrict__ ob, float* __restrict__ out, int N) {
  __shared__ float otile[TOK][TD + 1];
  const int tid = threadIdx.x;
  const int nt = N / TOK;
  const int b = blockIdx.x / nt;
  const int n0 = (blockIdx.x % nt) * TOK;
  const float* obase = O + ((size_t)(b * N + n0)) * TD;
  for (int idx = tid * 4; idx < TOK * TD; idx += 1024) {
    float4 v = *reinterpret_cast<const float4*>(obase + idx);
    int r = idx / TD, c = idx - r * TD;
    otile[r][c] = v.x; otile[r][c + 1] = v.y; otile[r][c + 2] = v.z; otile[r][c + 3] = v.w;
  }
  __syncthreads();
  const int nl = tid >> 2;            // 0..63 token
  const int ts = (tid & 3) * 48;      // output-channel group
  float acc[48];
#pragma unroll
  for (int i = 0; i < 48; ++i) acc[i] = 0.f;
  for (int c = 0; c < TD; ++c) {
    float oval = otile[nl][c];
    const float* wr = ow + c * TD + ts;
#pragma unroll
    for (int i = 0; i < 48; ++i) acc[i] = fmaf(oval, wr[i], acc[i]);
  }
#pragma unroll
  for (int i = 0; i < 48; ++i) {
    int t = ts + i;
    out[((size_t)(b * TD + t)) * N + n0 + nl] = acc[i] + ob[t];
  }
}

extern "C" void kernel_launch(void* const* d_in, const int* in_sizes, int n_in,
                              void* d_out, int out_size, void* d_ws, size_t ws_size,
                              hipStream_t stream) {
  const int B = 2;
  const int Cs[3] = {64, 128, 192};
  const int Hs[3] = {64, 32, 16};
  const size_t out_off[3] = {0,
                             (size_t)2 * TD * 64 * 64,
                             (size_t)2 * TD * 64 * 64 + (size_t)2 * TD * 32 * 32};

  float* ws = (float*)d_ws;
  float* pe = ws;                                 // 4096*192
  float* Q = pe + (size_t)4096 * TD;              // 2*4096*192
  float* Kt = Q + (size_t)B * 4096 * TD;
  float* V = Kt + (size_t)B * 4096 * TD;
  float* Obuf = V + (size_t)B * 4096 * TD;

  for (int lvl = 0; lvl < 3; ++lvl) {
    int C = Cs[lvl], H = Hs[lvl], W = H, N = H * W;
    const float* feat1 = (const float*)d_in[lvl * 2 + 0];
    const float* feat2 = (const float*)d_in[lvl * 2 + 1];
    const float* qw = (const float*)d_in[6 + lvl * 8 + 0];
    const float* qb = (const float*)d_in[6 + lvl * 8 + 1];
    const float* kw = (const float*)d_in[6 + lvl * 8 + 2];
    const float* kb = (const float*)d_in[6 + lvl * 8 + 3];
    const float* vw = (const float*)d_in[6 + lvl * 8 + 4];
    const float* vb = (const float*)d_in[6 + lvl * 8 + 5];
    const float* ow = (const float*)d_in[6 + lvl * 8 + 6];
    const float* ob = (const float*)d_in[6 + lvl * 8 + 7];

    pe_kernel<<<N, TD, 0, stream>>>(pe, W);
    qkv_kernel<<<B * N, TD, 0, stream>>>(feat1, feat2, qw, qb, kw, kb, vw, vb, pe, Q, Kt, V, C, N);
    size_t shm = (size_t)QB * N * sizeof(unsigned);
    int nblk = B * 4 * (N / QB);
    if (N == 4096)      attn_kernel<4096><<<nblk, 256, shm, stream>>>(Q, Kt, V, Obuf);
    else if (N == 1024) attn_kernel<1024><<<nblk, 256, shm, stream>>>(Q, Kt, V, Obuf);
    else                attn_kernel<256><<<nblk, 256, shm, stream>>>(Q, Kt, V, Obuf);
    oproj_kernel<<<B * (N / TOK), 256, 0, stream>>>(Obuf, ow, ob, (float*)d_out + out_off[lvl], N);
  }
}